// Round 1
// baseline (49.122 us; speedup 1.0000x reference)
//
#include <hip/hip_runtime.h>
#include <hip/hip_bf16.h>
#include <cstdint>
#include <cstddef>

// Problem constants
#define Bsz 16384
#define Esz 16
#define Ssz 64
#define Asz 32
#define Isz 96   // S + A
#define HSz 64
#define HRz 32

#define BT 128        // batch rows per block
#define NTHREADS 512  // 8 waves
#define XPAD 104      // row stride (bf16 elems) for Xs/W1T/rW1T: 208 B (16B-mult, 2-way banks)
#define HPAD 72       // row stride for Hs/W2T: 144 B (16B-mult)

typedef __attribute__((ext_vector_type(8))) short bf16x8;
typedef __attribute__((ext_vector_type(4))) short short4v;
typedef __attribute__((ext_vector_type(4))) float f32x4;

__device__ __forceinline__ short f2bf(float f) {
    union { float f; uint32_t u; } v; v.f = f;
    uint32_t r = v.u + 0x7fffu + ((v.u >> 16) & 1u);  // round-to-nearest-even
    return (short)(r >> 16);
}

__global__ __launch_bounds__(NTHREADS, 1)
void ensemble_fused(const float* __restrict__ state,
                    const float* __restrict__ action,
                    const float* __restrict__ W1, const float* __restrict__ b1,
                    const float* __restrict__ W2, const float* __restrict__ b2,
                    const float* __restrict__ rW1, const float* __restrict__ rb1,
                    const float* __restrict__ rW2, const float* __restrict__ rb2,
                    float* __restrict__ outS, float* __restrict__ outR)
{
    // LDS: 26624 + 13312 + 9216 + 6656 = 55808 B  -> 2 blocks/CU
    __shared__ __align__(16) short Xs[BT * XPAD];    // X tile (bf16); reused as H after L1
    __shared__ __align__(16) short W1T[HSz * XPAD];  // W1T[h][i]
    __shared__ __align__(16) short W2T[Ssz * HPAD];  // W2T[s][h]
    __shared__ __align__(16) short rW1T[HRz * XPAD]; // rW1T[h][i]

    const int tid = threadIdx.x;
    const int e  = blockIdx.x & (Esz - 1);        // consecutive blocks share X tile
    const int b0 = (blockIdx.x >> 4) * BT;

    // ---- Stage X tile: concat(state,action) -> bf16, row-major stride XPAD ----
    for (int idx = tid; idx < BT * 24; idx += NTHREADS) {
        int row = idx / 24, q = idx - row * 24;
        float4 v = (q < 16)
            ? ((const float4*)(state  + (size_t)(b0 + row) * Ssz))[q]
            : ((const float4*)(action + (size_t)(b0 + row) * Asz))[q - 16];
        short4v p = { f2bf(v.x), f2bf(v.y), f2bf(v.z), f2bf(v.w) };
        *(short4v*)&Xs[row * XPAD + q * 4] = p;
    }
    // ---- Stage transposed weights (bf16) ----
    const float* W1e = W1 + (size_t)e * Isz * HSz;
    for (int idx = tid; idx < Isz * HSz; idx += NTHREADS) {
        int i = idx >> 6, h = idx & 63;
        W1T[h * XPAD + i] = f2bf(W1e[idx]);
    }
    const float* W2e = W2 + (size_t)e * HSz * Ssz;
    for (int idx = tid; idx < HSz * Ssz; idx += NTHREADS) {
        int h = idx >> 6, s = idx & 63;
        W2T[s * HPAD + h] = f2bf(W2e[idx]);
    }
    const float* rW1e = rW1 + (size_t)e * Isz * HRz;
    for (int idx = tid; idx < Isz * HRz; idx += NTHREADS) {
        int i = idx >> 5, h = idx & 31;
        rW1T[h * XPAD + i] = f2bf(rW1e[idx]);
    }
    __syncthreads();

    const int lane = tid & 63;
    const int lr = lane & 15, lg = lane >> 4;
    const int m0 = (tid >> 6) * 16;    // 16 rows per wave

    // A-fragments: lane holds X[m0+lr][kk*32 + lg*8 .. +7]
    const short* xrow = &Xs[(m0 + lr) * XPAD + lg * 8];
    bf16x8 a0 = *(const bf16x8*)(xrow);
    bf16x8 a1 = *(const bf16x8*)(xrow + 32);
    bf16x8 a2 = *(const bf16x8*)(xrow + 64);

    f32x4 accS[4], accR[2];
    #pragma unroll
    for (int nt = 0; nt < 4; ++nt) accS[nt] = (f32x4){0.f, 0.f, 0.f, 0.f};
    #pragma unroll
    for (int nt = 0; nt < 2; ++nt) accR[nt] = (f32x4){0.f, 0.f, 0.f, 0.f};

    // ---- Layer 1 (state): H = X @ W1, K=96 ----
    #pragma unroll
    for (int nt = 0; nt < 4; ++nt) {
        const short* bp = &W1T[(nt * 16 + lr) * XPAD + lg * 8];
        accS[nt] = __builtin_amdgcn_mfma_f32_16x16x32_bf16(a0, *(const bf16x8*)(bp),      accS[nt], 0, 0, 0);
        accS[nt] = __builtin_amdgcn_mfma_f32_16x16x32_bf16(a1, *(const bf16x8*)(bp + 32), accS[nt], 0, 0, 0);
        accS[nt] = __builtin_amdgcn_mfma_f32_16x16x32_bf16(a2, *(const bf16x8*)(bp + 64), accS[nt], 0, 0, 0);
    }
    // ---- Layer 1 (reward): HR = X @ rW1, K=96 ----
    #pragma unroll
    for (int nt = 0; nt < 2; ++nt) {
        const short* bp = &rW1T[(nt * 16 + lr) * XPAD + lg * 8];
        accR[nt] = __builtin_amdgcn_mfma_f32_16x16x32_bf16(a0, *(const bf16x8*)(bp),      accR[nt], 0, 0, 0);
        accR[nt] = __builtin_amdgcn_mfma_f32_16x16x32_bf16(a1, *(const bf16x8*)(bp + 32), accR[nt], 0, 0, 0);
        accR[nt] = __builtin_amdgcn_mfma_f32_16x16x32_bf16(a2, *(const bf16x8*)(bp + 64), accR[nt], 0, 0, 0);
    }

    __syncthreads();   // all reads of Xs complete before overwriting with H

    // ---- H = relu(acc + b1) -> bf16 into Xs region (stride HPAD) ----
    short* Hs = Xs;
    #pragma unroll
    for (int nt = 0; nt < 4; ++nt) {
        float bias = b1[e * HSz + nt * 16 + lr];
        #pragma unroll
        for (int j = 0; j < 4; ++j) {
            float hv = fmaxf(accS[nt][j] + bias, 0.f);
            // D layout: row = lg*4 + j, col = nt*16 + lr
            Hs[(m0 + lg * 4 + j) * HPAD + nt * 16 + lr] = f2bf(hv);
        }
    }

    // ---- Reward layer 2 entirely in registers (N=1) ----
    float rp0 = 0.f, rp1 = 0.f, rp2 = 0.f, rp3 = 0.f;
    #pragma unroll
    for (int nt = 0; nt < 2; ++nt) {
        float biasr = rb1[e * HRz + nt * 16 + lr];
        float wr    = rW2[e * HRz + nt * 16 + lr];
        rp0 += fmaxf(accR[nt][0] + biasr, 0.f) * wr;
        rp1 += fmaxf(accR[nt][1] + biasr, 0.f) * wr;
        rp2 += fmaxf(accR[nt][2] + biasr, 0.f) * wr;
        rp3 += fmaxf(accR[nt][3] + biasr, 0.f) * wr;
    }
    #pragma unroll
    for (int d = 1; d < 16; d <<= 1) {   // reduce over lr (16 lanes)
        rp0 += __shfl_xor(rp0, d);
        rp1 += __shfl_xor(rp1, d);
        rp2 += __shfl_xor(rp2, d);
        rp3 += __shfl_xor(rp3, d);
    }
    if (lr == 0) {
        float rb = rb2[e];
        size_t base = (size_t)e * Bsz + b0 + m0 + lg * 4;
        outR[base + 0] = fminf(fmaxf(rp0 + rb, -100.f), 200.f);
        outR[base + 1] = fminf(fmaxf(rp1 + rb, -100.f), 200.f);
        outR[base + 2] = fminf(fmaxf(rp2 + rb, -100.f), 200.f);
        outR[base + 3] = fminf(fmaxf(rp3 + rb, -100.f), 200.f);
    }

    __syncthreads();   // H visible to all

    // ---- Layer 2 (state): OUT = H @ W2, K=64 ----
    const short* hrow = &Hs[(m0 + lr) * HPAD + lg * 8];
    bf16x8 h0 = *(const bf16x8*)(hrow);
    bf16x8 h1 = *(const bf16x8*)(hrow + 32);

    f32x4 accO[4];
    #pragma unroll
    for (int nt = 0; nt < 4; ++nt) accO[nt] = (f32x4){0.f, 0.f, 0.f, 0.f};
    #pragma unroll
    for (int nt = 0; nt < 4; ++nt) {
        const short* bp = &W2T[(nt * 16 + lr) * HPAD + lg * 8];
        accO[nt] = __builtin_amdgcn_mfma_f32_16x16x32_bf16(h0, *(const bf16x8*)(bp),      accO[nt], 0, 0, 0);
        accO[nt] = __builtin_amdgcn_mfma_f32_16x16x32_bf16(h1, *(const bf16x8*)(bp + 32), accO[nt], 0, 0, 0);
    }
    #pragma unroll
    for (int nt = 0; nt < 4; ++nt) {
        float bias = b2[e * Ssz + nt * 16 + lr];
        #pragma unroll
        for (int j = 0; j < 4; ++j) {
            size_t row = (size_t)e * Bsz + b0 + m0 + lg * 4 + j;
            outS[row * Ssz + nt * 16 + lr] = accO[nt][j] + bias;
        }
    }
}

extern "C" void kernel_launch(void* const* d_in, const int* in_sizes, int n_in,
                              void* d_out, int out_size, void* d_ws, size_t ws_size,
                              hipStream_t stream) {
    const float* state  = (const float*)d_in[0];
    const float* action = (const float*)d_in[1];
    const float* W1  = (const float*)d_in[2];
    const float* b1  = (const float*)d_in[3];
    const float* W2  = (const float*)d_in[4];
    const float* b2  = (const float*)d_in[5];
    const float* rW1 = (const float*)d_in[6];
    const float* rb1 = (const float*)d_in[7];
    const float* rW2 = (const float*)d_in[8];
    const float* rb2 = (const float*)d_in[9];

    float* outS = (float*)d_out;                         // [E, B, S]
    float* outR = outS + (size_t)Esz * Bsz * Ssz;        // [E, B, 1]

    dim3 grid(Esz * (Bsz / BT));   // 2048 blocks; e = bid & 15 for X-tile L2/L3 reuse
    ensemble_fused<<<grid, NTHREADS, 0, stream>>>(
        state, action, W1, b1, W2, b2, rW1, rb1, rW2, rb2, outS, outR);
}

// Round 2
// 38.311 us; speedup vs baseline: 1.2822x; 1.2822x over previous
//
#include <hip/hip_runtime.h>
#include <cstdint>
#include <cstddef>

// Problem constants
#define Bsz 16384
#define Esz 16
#define Ssz 64
#define Asz 32
#define Isz 96   // S + A
#define HSz 64
#define HRz 32

#define BT 128        // batch rows per block (8 waves x 16 rows)
#define NT 512

typedef __attribute__((ext_vector_type(8))) short bf16x8;
typedef __attribute__((ext_vector_type(4))) short short4v;
typedef __attribute__((ext_vector_type(4))) float f32x4;

__device__ __forceinline__ short f2bf(float f) {
    union { float f; uint32_t u; } v; v.f = f;
    uint32_t r = v.u + 0x7fffu + ((v.u >> 16) & 1u);  // RNE
    return (short)(r >> 16);
}

// Workspace layout (bytes)
#define OFF_XBF  0
#define SZ_XBF   (Bsz * Isz * 2)          // 3145728
#define OFF_W1F  (OFF_XBF + SZ_XBF)
#define SZ_W1F   (Esz * Isz * HSz * 2)    // 196608 (per-e 6144 elems)
#define OFF_RW1F (OFF_W1F + SZ_W1F)
#define SZ_RW1F  (Esz * Isz * HRz * 2)    // 98304 (per-e 3072)
#define OFF_W2F  (OFF_RW1F + SZ_RW1F)
#define SZ_W2F   (Esz * HSz * Ssz * 2)    // 131072 (per-e 4096)

// ---- Prep 1: X = concat(state,action) -> bf16 row-major [B][96] ----
__global__ void prep_x(const float* __restrict__ state, const float* __restrict__ action,
                       short* __restrict__ Xbf) {
    int idx = blockIdx.x * blockDim.x + threadIdx.x;   // [0, Bsz*24)
    int row = idx / 24, q = idx - row * 24;
    float4 v = (q < 16)
        ? ((const float4*)(state  + (size_t)row * Ssz))[q]
        : ((const float4*)(action + (size_t)row * Asz))[q - 16];
    short4v p = { f2bf(v.x), f2bf(v.y), f2bf(v.z), f2bf(v.w) };
    *(short4v*)&Xbf[(size_t)row * Isz + q * 4] = p;
}

// ---- Prep 2: weights -> bf16 in MFMA B-fragment order [e][nt][kk][lane][8] ----
// B-frag for 16x16x32: lane l holds B[k=(l>>4)*8+t][n=(l&15)], t=0..7
__global__ void prep_w(const float* __restrict__ W1, const float* __restrict__ rW1,
                       const float* __restrict__ W2,
                       short* __restrict__ W1f, short* __restrict__ rW1f, short* __restrict__ W2f) {
    int idx = blockIdx.x * blockDim.x + threadIdx.x;   // [0, Esz*13312)
    int e = idx / 13312, r = idx - e * 13312;
    if (r < 6144) {            // W1: [nt<4][kk<3][l][t], k=i, n=h
        int nt = r / 1536, r2 = r % 1536, kk = r2 / 512, r3 = r2 % 512, l = r3 >> 3, t = r3 & 7;
        int i = kk * 32 + (l >> 4) * 8 + t, h = nt * 16 + (l & 15);
        W1f[e * 6144 + r] = f2bf(W1[(size_t)e * Isz * HSz + i * HSz + h]);
    } else if (r < 9216) {     // rW1: [nt<2][kk<3][l][t], k=i, n=h
        int r1 = r - 6144;
        int nt = r1 / 1536, r2 = r1 % 1536, kk = r2 / 512, r3 = r2 % 512, l = r3 >> 3, t = r3 & 7;
        int i = kk * 32 + (l >> 4) * 8 + t, h = nt * 16 + (l & 15);
        rW1f[e * 3072 + r1] = f2bf(rW1[(size_t)e * Isz * HRz + i * HRz + h]);
    } else {                   // W2: [nt<4][kk<2][l][t], k=h, n=s
        int r1 = r - 9216;
        int nt = r1 / 1024, r2 = r1 % 1024, kk = r2 / 512, r3 = r2 % 512, l = r3 >> 3, t = r3 & 7;
        int hk = kk * 32 + (l >> 4) * 8 + t, s = nt * 16 + (l & 15);
        W2f[e * 4096 + r1] = f2bf(W2[(size_t)e * HSz * Ssz + hk * Ssz + s]);
    }
}

// ---- Main: barrier-free fused MLP ----
__global__ __launch_bounds__(NT, 4)
void ensemble_main(const short* __restrict__ Xbf, const short* __restrict__ W1f,
                   const short* __restrict__ rW1f, const short* __restrict__ W2f,
                   const float* __restrict__ b1, const float* __restrict__ b2,
                   const float* __restrict__ rb1, const float* __restrict__ rW2,
                   const float* __restrict__ rb2,
                   float* __restrict__ outS, float* __restrict__ outR)
{
    // Per-wave-private H transpose buffer. Row stride 20 shorts (40 B):
    // 8B-aligned b64 writes (optimal 4-cycle), reads 2-way (free). 20480 B total.
    __shared__ __align__(16) short HT[8][HSz][20];

    const int e  = blockIdx.x & (Esz - 1);   // 16 consecutive blocks share the X tile
    const int b0 = (blockIdx.x >> 4) * BT;
    const int w = threadIdx.x >> 6, lane = threadIdx.x & 63;
    const int lr = lane & 15, lg = lane >> 4;
    const int m0 = w * 16;

    // A-fragments straight from global (L2-warm: shared by 16 e-blocks)
    const short* xr = Xbf + (size_t)(b0 + m0 + lr) * Isz + lg * 8;
    bf16x8 a0 = *(const bf16x8*)(xr);
    bf16x8 a1 = *(const bf16x8*)(xr + 32);
    bf16x8 a2 = *(const bf16x8*)(xr + 64);

    // ---- Layer 1 (state): K=96 ----
    const short* w1p = W1f + e * 6144 + lane * 8;
    f32x4 accS[4];
    #pragma unroll
    for (int nt = 0; nt < 4; ++nt) {
        f32x4 acc = (f32x4){0.f, 0.f, 0.f, 0.f};
        acc = __builtin_amdgcn_mfma_f32_16x16x32_bf16(a0, *(const bf16x8*)(w1p + nt*1536),        acc, 0, 0, 0);
        acc = __builtin_amdgcn_mfma_f32_16x16x32_bf16(a1, *(const bf16x8*)(w1p + nt*1536 + 512),  acc, 0, 0, 0);
        acc = __builtin_amdgcn_mfma_f32_16x16x32_bf16(a2, *(const bf16x8*)(w1p + nt*1536 + 1024), acc, 0, 0, 0);
        accS[nt] = acc;
    }
    // ---- Layer 1 (reward): K=96 ----
    const short* rw1p = rW1f + e * 3072 + lane * 8;
    f32x4 accR[2];
    #pragma unroll
    for (int nt = 0; nt < 2; ++nt) {
        f32x4 acc = (f32x4){0.f, 0.f, 0.f, 0.f};
        acc = __builtin_amdgcn_mfma_f32_16x16x32_bf16(a0, *(const bf16x8*)(rw1p + nt*1536),        acc, 0, 0, 0);
        acc = __builtin_amdgcn_mfma_f32_16x16x32_bf16(a1, *(const bf16x8*)(rw1p + nt*1536 + 512),  acc, 0, 0, 0);
        acc = __builtin_amdgcn_mfma_f32_16x16x32_bf16(a2, *(const bf16x8*)(rw1p + nt*1536 + 1024), acc, 0, 0, 0);
        accR[nt] = acc;
    }

    // ---- Epilogue 1: H = relu(accS + b1) -> HT[w][h][m'] (packed b64, 4 m' per write) ----
    // D layout: value (nt,j) = H[m0 + lg*4 + j][nt*16 + lr]
    #pragma unroll
    for (int nt = 0; nt < 4; ++nt) {
        float bias = b1[e * HSz + nt * 16 + lr];
        short4v p = { f2bf(fmaxf(accS[nt][0] + bias, 0.f)),
                      f2bf(fmaxf(accS[nt][1] + bias, 0.f)),
                      f2bf(fmaxf(accS[nt][2] + bias, 0.f)),
                      f2bf(fmaxf(accS[nt][3] + bias, 0.f)) };
        *(short4v*)&HT[w][nt * 16 + lr][lg * 4] = p;
    }

    // ---- Reward layer 2 in registers (N=1) ----
    float rp[4] = {0.f, 0.f, 0.f, 0.f};
    #pragma unroll
    for (int nt = 0; nt < 2; ++nt) {
        float biasr = rb1[e * HRz + nt * 16 + lr];
        float wr    = rW2[e * HRz + nt * 16 + lr];
        #pragma unroll
        for (int j = 0; j < 4; ++j)
            rp[j] += fmaxf(accR[nt][j] + biasr, 0.f) * wr;
    }
    #pragma unroll
    for (int d = 1; d < 16; d <<= 1) {
        #pragma unroll
        for (int j = 0; j < 4; ++j) rp[j] += __shfl_xor(rp[j], d);
    }
    if (lr == 0) {
        float rb = rb2[e];
        size_t base = (size_t)e * Bsz + b0 + m0 + lg * 4;
        #pragma unroll
        for (int j = 0; j < 4; ++j)
            outR[base + j] = fminf(fmaxf(rp[j] + rb, -100.f), 200.f);
    }

    // ---- Layer 2 (state): K=64. HT is wave-private -> no barrier, lgkmcnt only ----
    bf16x8 h0, h1;
    #pragma unroll
    for (int t = 0; t < 8; ++t) {
        h0[t] = HT[w][lg * 8 + t][lr];
        h1[t] = HT[w][32 + lg * 8 + t][lr];
    }
    const short* w2p = W2f + e * 4096 + lane * 8;
    #pragma unroll
    for (int nt = 0; nt < 4; ++nt) {
        f32x4 acc = (f32x4){0.f, 0.f, 0.f, 0.f};
        acc = __builtin_amdgcn_mfma_f32_16x16x32_bf16(h0, *(const bf16x8*)(w2p + nt*1024),       acc, 0, 0, 0);
        acc = __builtin_amdgcn_mfma_f32_16x16x32_bf16(h1, *(const bf16x8*)(w2p + nt*1024 + 512), acc, 0, 0, 0);
        float bias = b2[e * Ssz + nt * 16 + lr];
        #pragma unroll
        for (int j = 0; j < 4; ++j) {
            size_t row = (size_t)e * Bsz + b0 + m0 + lg * 4 + j;
            outS[row * Ssz + nt * 16 + lr] = acc[j] + bias;
        }
    }
}

extern "C" void kernel_launch(void* const* d_in, const int* in_sizes, int n_in,
                              void* d_out, int out_size, void* d_ws, size_t ws_size,
                              hipStream_t stream) {
    const float* state  = (const float*)d_in[0];
    const float* action = (const float*)d_in[1];
    const float* W1  = (const float*)d_in[2];
    const float* b1  = (const float*)d_in[3];
    const float* W2  = (const float*)d_in[4];
    const float* b2  = (const float*)d_in[5];
    const float* rW1 = (const float*)d_in[6];
    const float* rb1 = (const float*)d_in[7];
    const float* rW2 = (const float*)d_in[8];
    const float* rb2 = (const float*)d_in[9];

    float* outS = (float*)d_out;                      // [E, B, S]
    float* outR = outS + (size_t)Esz * Bsz * Ssz;     // [E, B, 1]

    short* Xbf  = (short*)((char*)d_ws + OFF_XBF);
    short* W1f  = (short*)((char*)d_ws + OFF_W1F);
    short* rW1f = (short*)((char*)d_ws + OFF_RW1F);
    short* W2f  = (short*)((char*)d_ws + OFF_W2F);

    prep_x<<<(Bsz * 24) / NT, NT, 0, stream>>>(state, action, Xbf);           // 768 blocks
    prep_w<<<(Esz * 13312) / NT, NT, 0, stream>>>(W1, rW1, W2, W1f, rW1f, W2f); // 416 blocks
    ensemble_main<<<Esz * (Bsz / BT), NT, 0, stream>>>(                        // 2048 blocks
        Xbf, W1f, rW1f, W2f, b1, b2, rb1, rW2, rb2, outS, outR);
}

// Round 3
// 35.994 us; speedup vs baseline: 1.3647x; 1.0644x over previous
//
#include <hip/hip_runtime.h>
#include <hip/hip_bf16.h>
#include <cstdint>
#include <cstddef>

// Problem constants
#define Bsz 16384
#define Esz 16
#define Ssz 64
#define Asz 32
#define Isz 96   // S + A
#define HSz 64
#define HRz 32

#define BT 128        // batch rows per block (8 waves x 16 rows)
#define ET 4          // ensembles per block (rolled loop)
#define NT 512

typedef __attribute__((ext_vector_type(8))) short bf16x8;
typedef __attribute__((ext_vector_type(4))) short short4v;
typedef __attribute__((ext_vector_type(4))) float f32x4;

__device__ __forceinline__ short f2bf(float f) {
    __hip_bfloat16 b = __float2bfloat16(f);   // compiler pairs adjacent casts into v_cvt_pk_bf16_f32
    return *reinterpret_cast<short*>(&b);
}

// Workspace layout (bytes)
#define OFF_XBF  0
#define SZ_XBF   (Bsz * Isz * 2)          // 3145728
#define OFF_W1F  (OFF_XBF + SZ_XBF)
#define SZ_W1F   (Esz * Isz * HSz * 2)    // 196608 (per-e 6144 elems)
#define OFF_RW1F (OFF_W1F + SZ_W1F)
#define SZ_RW1F  (Esz * Isz * HRz * 2)    // 98304 (per-e 3072)
#define OFF_W2F  (OFF_RW1F + SZ_RW1F)
#define SZ_W2F   (Esz * HSz * Ssz * 2)    // 131072 (per-e 4096)

// ---- Prep 1: X = concat(state,action) -> bf16 row-major [B][96] ----
__global__ void prep_x(const float* __restrict__ state, const float* __restrict__ action,
                       short* __restrict__ Xbf) {
    int idx = blockIdx.x * blockDim.x + threadIdx.x;   // [0, Bsz*24)
    int row = idx / 24, q = idx - row * 24;
    float4 v = (q < 16)
        ? ((const float4*)(state  + (size_t)row * Ssz))[q]
        : ((const float4*)(action + (size_t)row * Asz))[q - 16];
    short4v p = { f2bf(v.x), f2bf(v.y), f2bf(v.z), f2bf(v.w) };
    *(short4v*)&Xbf[(size_t)row * Isz + q * 4] = p;
}

// ---- Prep 2: weights -> bf16 in MFMA B-fragment order [e][nt][kk][lane][8] ----
// B-frag for 16x16x32: lane l holds B[k=(l>>4)*8+t][n=(l&15)], t=0..7
__global__ void prep_w(const float* __restrict__ W1, const float* __restrict__ rW1,
                       const float* __restrict__ W2,
                       short* __restrict__ W1f, short* __restrict__ rW1f, short* __restrict__ W2f) {
    int idx = blockIdx.x * blockDim.x + threadIdx.x;   // [0, Esz*13312)
    int e = idx / 13312, r = idx - e * 13312;
    if (r < 6144) {            // W1: [nt<4][kk<3][l][t], k=i, n=h
        int nt = r / 1536, r2 = r % 1536, kk = r2 / 512, r3 = r2 % 512, l = r3 >> 3, t = r3 & 7;
        int i = kk * 32 + (l >> 4) * 8 + t, h = nt * 16 + (l & 15);
        W1f[e * 6144 + r] = f2bf(W1[(size_t)e * Isz * HSz + i * HSz + h]);
    } else if (r < 9216) {     // rW1: [nt<2][kk<3][l][t], k=i, n=h
        int r1 = r - 6144;
        int nt = r1 / 1536, r2 = r1 % 1536, kk = r2 / 512, r3 = r2 % 512, l = r3 >> 3, t = r3 & 7;
        int i = kk * 32 + (l >> 4) * 8 + t, h = nt * 16 + (l & 15);
        rW1f[e * 3072 + r1] = f2bf(rW1[(size_t)e * Isz * HRz + i * HRz + h]);
    } else {                   // W2: [nt<4][kk<2][l][t], k=h, n=s
        int r1 = r - 9216;
        int nt = r1 / 1024, r2 = r1 % 1024, kk = r2 / 512, r3 = r2 % 512, l = r3 >> 3, t = r3 & 7;
        int hk = kk * 32 + (l >> 4) * 8 + t, s = nt * 16 + (l & 15);
        W2f[e * 4096 + r1] = f2bf(W2[(size_t)e * HSz * Ssz + hk * Ssz + s]);
    }
}

// ---- Main: barrier-free fused MLP, ET ensembles per block (rolled loop) ----
__global__ __launch_bounds__(NT, 4)
void ensemble_main(const short* __restrict__ Xbf, const short* __restrict__ W1f,
                   const short* __restrict__ rW1f, const short* __restrict__ W2f,
                   const float* __restrict__ b1, const float* __restrict__ b2,
                   const float* __restrict__ rb1, const float* __restrict__ rW2,
                   const float* __restrict__ rb2,
                   float* __restrict__ outS, float* __restrict__ outR)
{
    // Per-wave-private H transpose buffer (reused each e-iteration).
    // Row stride 20 shorts (40 B): 8B-aligned b64 writes, reads 2-way (free). 20480 B.
    __shared__ __align__(16) short HT[8][HSz][20];

    const int e0 = (blockIdx.x & (Esz / ET - 1)) * ET;   // 4 consecutive blocks share X tile
    const int b0 = (blockIdx.x / (Esz / ET)) * BT;
    const int w = threadIdx.x >> 6, lane = threadIdx.x & 63;
    const int lr = lane & 15, lg = lane >> 4;
    const int m0 = w * 16;

    // A-fragments once, reused for all ET ensembles (L2/L3-warm)
    const short* xr = Xbf + (size_t)(b0 + m0 + lr) * Isz + lg * 8;
    bf16x8 a0 = *(const bf16x8*)(xr);
    bf16x8 a1 = *(const bf16x8*)(xr + 32);
    bf16x8 a2 = *(const bf16x8*)(xr + 64);

    #pragma unroll 1
    for (int ei = 0; ei < ET; ++ei) {
        const int e = e0 + ei;

        // ---- Layer 1 (state): K=96 ----
        const short* w1p = W1f + e * 6144 + lane * 8;
        f32x4 accS[4];
        #pragma unroll
        for (int nt = 0; nt < 4; ++nt) {
            f32x4 acc = (f32x4){0.f, 0.f, 0.f, 0.f};
            acc = __builtin_amdgcn_mfma_f32_16x16x32_bf16(a0, *(const bf16x8*)(w1p + nt*1536),        acc, 0, 0, 0);
            acc = __builtin_amdgcn_mfma_f32_16x16x32_bf16(a1, *(const bf16x8*)(w1p + nt*1536 + 512),  acc, 0, 0, 0);
            acc = __builtin_amdgcn_mfma_f32_16x16x32_bf16(a2, *(const bf16x8*)(w1p + nt*1536 + 1024), acc, 0, 0, 0);
            accS[nt] = acc;
        }
        // ---- Layer 1 (reward): K=96 ----
        const short* rw1p = rW1f + e * 3072 + lane * 8;
        f32x4 accR[2];
        #pragma unroll
        for (int nt = 0; nt < 2; ++nt) {
            f32x4 acc = (f32x4){0.f, 0.f, 0.f, 0.f};
            acc = __builtin_amdgcn_mfma_f32_16x16x32_bf16(a0, *(const bf16x8*)(rw1p + nt*1536),        acc, 0, 0, 0);
            acc = __builtin_amdgcn_mfma_f32_16x16x32_bf16(a1, *(const bf16x8*)(rw1p + nt*1536 + 512),  acc, 0, 0, 0);
            acc = __builtin_amdgcn_mfma_f32_16x16x32_bf16(a2, *(const bf16x8*)(rw1p + nt*1536 + 1024), acc, 0, 0, 0);
            accR[nt] = acc;
        }

        // ---- Epilogue 1: H = relu(accS + b1) -> HT[w][h][m'] (packed b64) ----
        // D layout: value (nt,j) = H[m0 + lg*4 + j][nt*16 + lr]
        #pragma unroll
        for (int nt = 0; nt < 4; ++nt) {
            float bias = b1[e * HSz + nt * 16 + lr];
            short4v p = { f2bf(fmaxf(accS[nt][0] + bias, 0.f)),
                          f2bf(fmaxf(accS[nt][1] + bias, 0.f)),
                          f2bf(fmaxf(accS[nt][2] + bias, 0.f)),
                          f2bf(fmaxf(accS[nt][3] + bias, 0.f)) };
            *(short4v*)&HT[w][nt * 16 + lr][lg * 4] = p;
        }

        // ---- Reward layer 2 in registers (N=1) ----
        float rp[4] = {0.f, 0.f, 0.f, 0.f};
        #pragma unroll
        for (int nt = 0; nt < 2; ++nt) {
            float biasr = rb1[e * HRz + nt * 16 + lr];
            float wr    = rW2[e * HRz + nt * 16 + lr];
            #pragma unroll
            for (int j = 0; j < 4; ++j)
                rp[j] += fmaxf(accR[nt][j] + biasr, 0.f) * wr;
        }
        #pragma unroll
        for (int d = 1; d < 16; d <<= 1) {
            #pragma unroll
            for (int j = 0; j < 4; ++j) rp[j] += __shfl_xor(rp[j], d);
        }
        if (lr == 0) {
            float rb = rb2[e];
            size_t base = (size_t)e * Bsz + b0 + m0 + lg * 4;
            #pragma unroll
            for (int j = 0; j < 4; ++j)
                outR[base + j] = fminf(fmaxf(rp[j] + rb, -100.f), 200.f);
        }

        // ---- Layer 2 (state): K=64. HT wave-private -> lgkmcnt only, no barrier ----
        bf16x8 h0, h1;
        #pragma unroll
        for (int t = 0; t < 8; ++t) {
            h0[t] = HT[w][lg * 8 + t][lr];
            h1[t] = HT[w][32 + lg * 8 + t][lr];
        }
        const short* w2p = W2f + e * 4096 + lane * 8;
        #pragma unroll
        for (int nt = 0; nt < 4; ++nt) {
            f32x4 acc = (f32x4){0.f, 0.f, 0.f, 0.f};
            acc = __builtin_amdgcn_mfma_f32_16x16x32_bf16(h0, *(const bf16x8*)(w2p + nt*1024),       acc, 0, 0, 0);
            acc = __builtin_amdgcn_mfma_f32_16x16x32_bf16(h1, *(const bf16x8*)(w2p + nt*1024 + 512), acc, 0, 0, 0);
            float bias = b2[e * Ssz + nt * 16 + lr];
            #pragma unroll
            for (int j = 0; j < 4; ++j) {
                size_t row = (size_t)e * Bsz + b0 + m0 + lg * 4 + j;
                outS[row * Ssz + nt * 16 + lr] = acc[j] + bias;
            }
        }
    }
}

extern "C" void kernel_launch(void* const* d_in, const int* in_sizes, int n_in,
                              void* d_out, int out_size, void* d_ws, size_t ws_size,
                              hipStream_t stream) {
    const float* state  = (const float*)d_in[0];
    const float* action = (const float*)d_in[1];
    const float* W1  = (const float*)d_in[2];
    const float* b1  = (const float*)d_in[3];
    const float* W2  = (const float*)d_in[4];
    const float* b2  = (const float*)d_in[5];
    const float* rW1 = (const float*)d_in[6];
    const float* rb1 = (const float*)d_in[7];
    const float* rW2 = (const float*)d_in[8];
    const float* rb2 = (const float*)d_in[9];

    float* outS = (float*)d_out;                      // [E, B, S]
    float* outR = outS + (size_t)Esz * Bsz * Ssz;     // [E, B, 1]

    short* Xbf  = (short*)((char*)d_ws + OFF_XBF);
    short* W1f  = (short*)((char*)d_ws + OFF_W1F);
    short* rW1f = (short*)((char*)d_ws + OFF_RW1F);
    short* W2f  = (short*)((char*)d_ws + OFF_W2F);

    prep_x<<<(Bsz * 24) / NT, NT, 0, stream>>>(state, action, Xbf);             // 768 blocks
    prep_w<<<(Esz * 13312) / NT, NT, 0, stream>>>(W1, rW1, W2, W1f, rW1f, W2f); // 416 blocks
    ensemble_main<<<(Esz / ET) * (Bsz / BT), NT, 0, stream>>>(                  // 512 blocks
        Xbf, W1f, rW1f, W2f, b1, b2, rb1, rW2, rb2, outS, outR);
}

// Round 4
// 30.243 us; speedup vs baseline: 1.6243x; 1.1902x over previous
//
#include <hip/hip_runtime.h>
#include <hip/hip_bf16.h>
#include <cstdint>
#include <cstddef>

// Problem constants
#define Bsz 16384
#define Esz 16
#define Ssz 64
#define Asz 32
#define Isz 96   // S + A
#define HSz 64
#define HRz 32

#define PT 512        // prep threads
#define NTM 256       // main threads (4 waves)
#define CHUNK 512     // batch rows per main block
#define NTILE 8       // CHUNK / (4 waves * 16 rows)

typedef __attribute__((ext_vector_type(8))) short bf16x8;
typedef __attribute__((ext_vector_type(4))) short short4v;
typedef __attribute__((ext_vector_type(4))) float f32x4;

__device__ __forceinline__ short f2bf(float f) {
    __hip_bfloat16 b = __float2bfloat16(f);   // pairs into v_cvt_pk_bf16_f32
    return *reinterpret_cast<short*>(&b);
}

// Workspace layout (bytes)
#define OFF_XBF  0
#define SZ_XBF   (Bsz * Isz * 2)          // 3145728
#define OFF_W1F  (OFF_XBF + SZ_XBF)
#define SZ_W1F   (Esz * Isz * HSz * 2)    // per-e 6144 elems
#define OFF_RW1F (OFF_W1F + SZ_W1F)
#define SZ_RW1F  (Esz * Isz * HRz * 2)    // per-e 3072
#define OFF_W2F  (OFF_RW1F + SZ_RW1F)
#define SZ_W2F   (Esz * HSz * Ssz * 2)    // per-e 4096

// ---- Prep (merged): X -> bf16 row-major; weights -> bf16 MFMA fragment order ----
// Fragment order [e][nt][kk][lane][8]: lane l holds W[k=kk*32+(l>>4)*8+t][n=nt*16+(l&15)]
__global__ void prep_all(const float* __restrict__ state, const float* __restrict__ action,
                         const float* __restrict__ W1, const float* __restrict__ rW1,
                         const float* __restrict__ W2,
                         short* __restrict__ Xbf, short* __restrict__ W1f,
                         short* __restrict__ rW1f, short* __restrict__ W2f) {
    int bid = blockIdx.x;
    if (bid < (Bsz * 24) / PT) {
        int idx = bid * PT + threadIdx.x;            // [0, Bsz*24)
        int row = idx / 24, q = idx - row * 24;
        float4 v = (q < 16)
            ? ((const float4*)(state  + (size_t)row * Ssz))[q]
            : ((const float4*)(action + (size_t)row * Asz))[q - 16];
        short4v p = { f2bf(v.x), f2bf(v.y), f2bf(v.z), f2bf(v.w) };
        *(short4v*)&Xbf[(size_t)row * Isz + q * 4] = p;
    } else {
        int idx = (bid - (Bsz * 24) / PT) * PT + threadIdx.x;  // [0, Esz*13312)
        int e = idx / 13312, r = idx - e * 13312;
        if (r < 6144) {            // W1: [nt<4][kk<3][l][t], k=i, n=h
            int nt = r / 1536, r2 = r % 1536, kk = r2 / 512, r3 = r2 % 512, l = r3 >> 3, t = r3 & 7;
            int i = kk * 32 + (l >> 4) * 8 + t, h = nt * 16 + (l & 15);
            W1f[e * 6144 + r] = f2bf(W1[(size_t)e * Isz * HSz + i * HSz + h]);
        } else if (r < 9216) {     // rW1: [nt<2][kk<3][l][t]
            int r1 = r - 6144;
            int nt = r1 / 1536, r2 = r1 % 1536, kk = r2 / 512, r3 = r2 % 512, l = r3 >> 3, t = r3 & 7;
            int i = kk * 32 + (l >> 4) * 8 + t, h = nt * 16 + (l & 15);
            rW1f[e * 3072 + r1] = f2bf(rW1[(size_t)e * Isz * HRz + i * HRz + h]);
        } else {                   // W2: [nt<4][kk<2][l][t], k=h, n=s
            int r1 = r - 9216;
            int nt = r1 / 1024, r2 = r1 % 1024, kk = r2 / 512, r3 = r2 % 512, l = r3 >> 3, t = r3 & 7;
            int hk = kk * 32 + (l >> 4) * 8 + t, s = nt * 16 + (l & 15);
            W2f[e * 4096 + r1] = f2bf(W2[(size_t)e * HSz * Ssz + hk * Ssz + s]);
        }
    }
}

// ---- Main: one ensemble per block, weights in VGPRs, swapped-operand MFMAs ----
// Swapped mfma(Wfrag, Xfrag): D[n_block][m] with lane: m = lane&15, n = nt*16 + (lane>>4)*4 + j.
__global__ __launch_bounds__(NTM, 2)
void ensemble_main(const short* __restrict__ Xbf, const short* __restrict__ W1f,
                   const short* __restrict__ rW1f, const short* __restrict__ W2f,
                   const float* __restrict__ b1, const float* __restrict__ b2,
                   const float* __restrict__ rb1, const float* __restrict__ rW2,
                   const float* __restrict__ rb2,
                   float* __restrict__ outS, float* __restrict__ outR)
{
    // Per-wave H buffer [m=16][h=64], row stride 68 shorts (136 B):
    // b64 writes and b128 reads both bank-perfect. 4*16*68*2 = 8704 B.
    __shared__ __align__(16) short HT[4][16][68];

    const int e  = blockIdx.x & (Esz - 1);       // 16 consecutive blocks share X rows
    const int c0 = (blockIdx.x >> 4) * CHUNK;
    const int w = threadIdx.x >> 6, lane = threadIdx.x & 63;
    const int lr = lane & 15, lg = lane >> 4;

    // ---- Loop-invariant: weight fragments into VGPRs ----
    bf16x8 w1r[4][3], rw1r[2][3], w2r[4][2];
    {
        const short* p = W1f + e * 6144 + lane * 8;
        #pragma unroll
        for (int nt = 0; nt < 4; ++nt)
            #pragma unroll
            for (int kk = 0; kk < 3; ++kk)
                w1r[nt][kk] = *(const bf16x8*)(p + (nt * 3 + kk) * 512);
    }
    {
        const short* p = rW1f + e * 3072 + lane * 8;
        #pragma unroll
        for (int nt = 0; nt < 2; ++nt)
            #pragma unroll
            for (int kk = 0; kk < 3; ++kk)
                rw1r[nt][kk] = *(const bf16x8*)(p + (nt * 3 + kk) * 512);
    }
    {
        const short* p = W2f + e * 4096 + lane * 8;
        #pragma unroll
        for (int nt = 0; nt < 4; ++nt)
            #pragma unroll
            for (int kk = 0; kk < 2; ++kk)
                w2r[nt][kk] = *(const bf16x8*)(p + (nt * 2 + kk) * 512);
    }
    // ---- Loop-invariant: biases (per-lane, match swapped D layout: n = nt*16+lg*4+j) ----
    float4 b1v[4], b2v[4], rb1v[2], rw2v[2];
    #pragma unroll
    for (int nt = 0; nt < 4; ++nt) {
        b1v[nt] = *(const float4*)&b1[e * HSz + nt * 16 + lg * 4];
        b2v[nt] = *(const float4*)&b2[e * Ssz + nt * 16 + lg * 4];
    }
    #pragma unroll
    for (int nt = 0; nt < 2; ++nt) {
        rb1v[nt] = *(const float4*)&rb1[e * HRz + nt * 16 + lg * 4];
        rw2v[nt] = *(const float4*)&rW2[e * HRz + nt * 16 + lg * 4];
    }
    const float rb2s = rb2[e];

    #pragma unroll 1
    for (int t = 0; t < NTILE; ++t) {
        const int mrow = c0 + t * 64 + w * 16 + lr;   // this lane's batch row (m = lr)

        // A-operands of X (same data serves as B-operand in swapped mfma)
        const short* xr = Xbf + (size_t)mrow * Isz + lg * 8;
        bf16x8 a0 = *(const bf16x8*)(xr);
        bf16x8 a1 = *(const bf16x8*)(xr + 32);
        bf16x8 a2 = *(const bf16x8*)(xr + 64);

        // ---- Layer 1 (state): D = H^T, lane: m=lr, h=nt*16+lg*4+j ----
        f32x4 accS[4];
        #pragma unroll
        for (int nt = 0; nt < 4; ++nt) {
            f32x4 acc = (f32x4){0.f, 0.f, 0.f, 0.f};
            acc = __builtin_amdgcn_mfma_f32_16x16x32_bf16(w1r[nt][0], a0, acc, 0, 0, 0);
            acc = __builtin_amdgcn_mfma_f32_16x16x32_bf16(w1r[nt][1], a1, acc, 0, 0, 0);
            acc = __builtin_amdgcn_mfma_f32_16x16x32_bf16(w1r[nt][2], a2, acc, 0, 0, 0);
            accS[nt] = acc;
        }
        // ---- Layer 1 (reward) ----
        f32x4 accR[2];
        #pragma unroll
        for (int nt = 0; nt < 2; ++nt) {
            f32x4 acc = (f32x4){0.f, 0.f, 0.f, 0.f};
            acc = __builtin_amdgcn_mfma_f32_16x16x32_bf16(rw1r[nt][0], a0, acc, 0, 0, 0);
            acc = __builtin_amdgcn_mfma_f32_16x16x32_bf16(rw1r[nt][1], a1, acc, 0, 0, 0);
            acc = __builtin_amdgcn_mfma_f32_16x16x32_bf16(rw1r[nt][2], a2, acc, 0, 0, 0);
            accR[nt] = acc;
        }

        // ---- H = relu(accS + b1): lane holds 4 consecutive h of row lr -> b64 write ----
        #pragma unroll
        for (int nt = 0; nt < 4; ++nt) {
            short4v p = { f2bf(fmaxf(accS[nt][0] + b1v[nt].x, 0.f)),
                          f2bf(fmaxf(accS[nt][1] + b1v[nt].y, 0.f)),
                          f2bf(fmaxf(accS[nt][2] + b1v[nt].z, 0.f)),
                          f2bf(fmaxf(accS[nt][3] + b1v[nt].w, 0.f)) };
            *(short4v*)&HT[w][lr][nt * 16 + lg * 4] = p;
        }

        // ---- Reward layer 2: per-lane partial over its 8 h, reduce across lg ----
        float rp = 0.f;
        #pragma unroll
        for (int nt = 0; nt < 2; ++nt) {
            rp += fmaxf(accR[nt][0] + rb1v[nt].x, 0.f) * rw2v[nt].x;
            rp += fmaxf(accR[nt][1] + rb1v[nt].y, 0.f) * rw2v[nt].y;
            rp += fmaxf(accR[nt][2] + rb1v[nt].z, 0.f) * rw2v[nt].z;
            rp += fmaxf(accR[nt][3] + rb1v[nt].w, 0.f) * rw2v[nt].w;
        }
        rp += __shfl_xor(rp, 16);
        rp += __shfl_xor(rp, 32);
        if (lane < 16)
            outR[(size_t)e * Bsz + mrow] = fminf(fmaxf(rp + rb2s, -100.f), 200.f);

        // ---- Layer 2 (state): H frags via b128 reads (wave-private, in-order DS) ----
        bf16x8 h0 = *(const bf16x8*)&HT[w][lr][lg * 8];
        bf16x8 h1 = *(const bf16x8*)&HT[w][lr][32 + lg * 8];
        #pragma unroll
        for (int nt = 0; nt < 4; ++nt) {
            f32x4 acc = (f32x4){0.f, 0.f, 0.f, 0.f};
            acc = __builtin_amdgcn_mfma_f32_16x16x32_bf16(w2r[nt][0], h0, acc, 0, 0, 0);
            acc = __builtin_amdgcn_mfma_f32_16x16x32_bf16(w2r[nt][1], h1, acc, 0, 0, 0);
            float4 o = { acc[0] + b2v[nt].x, acc[1] + b2v[nt].y,
                         acc[2] + b2v[nt].z, acc[3] + b2v[nt].w };
            // D: lane m=lr, s = nt*16 + lg*4 + j  -> 4 consecutive s = float4 store
            *(float4*)&outS[((size_t)e * Bsz + mrow) * Ssz + nt * 16 + lg * 4] = o;
        }
    }
}

extern "C" void kernel_launch(void* const* d_in, const int* in_sizes, int n_in,
                              void* d_out, int out_size, void* d_ws, size_t ws_size,
                              hipStream_t stream) {
    const float* state  = (const float*)d_in[0];
    const float* action = (const float*)d_in[1];
    const float* W1  = (const float*)d_in[2];
    const float* b1  = (const float*)d_in[3];
    const float* W2  = (const float*)d_in[4];
    const float* b2  = (const float*)d_in[5];
    const float* rW1 = (const float*)d_in[6];
    const float* rb1 = (const float*)d_in[7];
    const float* rW2 = (const float*)d_in[8];
    const float* rb2 = (const float*)d_in[9];

    float* outS = (float*)d_out;                      // [E, B, S]
    float* outR = outS + (size_t)Esz * Bsz * Ssz;     // [E, B, 1]

    short* Xbf  = (short*)((char*)d_ws + OFF_XBF);
    short* W1f  = (short*)((char*)d_ws + OFF_W1F);
    short* rW1f = (short*)((char*)d_ws + OFF_RW1F);
    short* W2f  = (short*)((char*)d_ws + OFF_W2F);

    const int prep_blocks = (Bsz * 24) / PT + (Esz * 13312) / PT;   // 768 + 416
    prep_all<<<prep_blocks, PT, 0, stream>>>(state, action, W1, rW1, W2,
                                             Xbf, W1f, rW1f, W2f);
    ensemble_main<<<Esz * (Bsz / CHUNK), NTM, 0, stream>>>(          // 512 blocks
        Xbf, W1f, rW1f, W2f, b1, b2, rb1, rW2, rb2, outS, outR);
}